// Round 10
// baseline (326.791 us; speedup 1.0000x reference)
//
#include <hip/hip_runtime.h>

typedef __attribute__((ext_vector_type(8))) short bf16x8;
typedef __attribute__((ext_vector_type(4))) float f32x4;

__device__ __forceinline__ unsigned short f2bf(float f){
  unsigned u = __builtin_bit_cast(unsigned, f);
  u += 0x7fffu + ((u >> 16) & 1u);
  return (unsigned short)(u >> 16);
}

__device__ __forceinline__ unsigned cvt_pk_bf16(float lo, float hi){
  unsigned r;
  asm("v_cvt_pk_bf16_f32 %0, %1, %2" : "=v"(r) : "v"(lo), "v"(hi));
  return r;
}

#define ASYNC16(ldsp, gp) __builtin_amdgcn_global_load_lds( \
    (const __attribute__((address_space(1))) unsigned int*)(gp), \
    (__attribute__((address_space(3))) unsigned int*)(ldsp), 16, 0, 0)

// ---- convert x (fp32 [b,56,56,384]) -> bf16 window-ordered [win*49+n][384] ----
__global__ __launch_bounds__(256) void convert_x_kernel(const float* __restrict__ x,
                                                        unsigned short* __restrict__ xb){
  int idx = blockIdx.x*256 + threadIdx.x;          // 100352*96 threads, 4 ch each
  int token = idx / 96, j = idx - token*96;
  int b = token / 3136, rem = token - b*3136;
  int rr = rem / 56, cp = rem - rr*56;
  int p = rr >> 3, h = rr & 7, q = cp >> 3, w = cp & 7;
  int orow = ((b*8 + h)*8 + w)*49 + p*7 + q;
  float4 v = *(const float4*)(x + (size_t)idx*4);
  ushort4 o;
  o.x = f2bf(v.x); o.y = f2bf(v.y); o.z = f2bf(v.z); o.w = f2bf(v.w);
  *(ushort4*)(xb + (size_t)orow*384 + j*4) = o;
}

// ---- convert weights fp32 -> bf16 ----
__global__ __launch_bounds__(256) void convert_w_kernel(const float* __restrict__ wq,
                                                        const float* __restrict__ wo,
                                                        unsigned short* __restrict__ wqb,
                                                        unsigned short* __restrict__ wob){
  int idx = blockIdx.x*256 + threadIdx.x;          // 147456 threads
  if (idx < 110592){
    float4 v = *(const float4*)(wq + (size_t)idx*4);
    ushort4 o; o.x=f2bf(v.x); o.y=f2bf(v.y); o.z=f2bf(v.z); o.w=f2bf(v.w);
    *(ushort4*)(wqb + (size_t)idx*4) = o;
  } else {
    int k = idx - 110592;
    float4 v = *(const float4*)(wo + (size_t)k*4);
    ushort4 o; o.x=f2bf(v.x); o.y=f2bf(v.y); o.z=f2bf(v.z); o.w=f2bf(v.w);
    *(ushort4*)(wob + (size_t)k*4) = o;
  }
}

// ---- bias table, FRAGMENT-major: btab[head][fi=ti*4+tj][lane][r] (f32),
// log2(e)-pre-scaled; -inf for k>=49 (mask); 0 for q>=49. Coalesced b128 loads. ----
__global__ __launch_bounds__(256) void build_btab(const float* __restrict__ rel_pos,
                                                  float* __restrict__ btab){
  int idx = blockIdx.x*256 + threadIdx.x;          // 12288 threads
  int head = idx >> 10, rem = idx & 1023;
  int fi = rem >> 6, lane = rem & 63;
  int ti = fi >> 2, tj = fi & 3;
  int qq = tj*16 + (lane & 15);
  int kb = ti*16 + (lane >> 4)*4;
  float4 v; float* vp = (float*)&v;
#pragma unroll
  for (int r=0; r<4; ++r){
    int kk = kb + r;
    float val;
    if (kk >= 49) val = -__builtin_inff();
    else if (qq >= 49) val = 0.f;
    else {
      int ip = qq/7, iq = qq - ip*7, jp = kk/7, jq = kk - jp*7;
      val = rel_pos[head*169 + (ip-jp+6)*13 + (iq-jq+6)] * 1.4426950408889634f;
    }
    vp[r] = val;
  }
  *(float4*)(btab + (size_t)idx*4) = v;
}

// ---- phase-split 8-wave GEMM (m201-template port): C = A @ B^T + bias.
// BM=256 BN=128 BK=64, 512 threads = 8 waves (4M x 2N), per-wave 64x64,
// triple-buffered LDS (144 KiB, 1 block/CU). Per K-tile: 2 phases, each
// {ds_reads + 3 stage-issues(tile t+2) -> barrier -> setprio+16 MFMA -> barrier};
// counted vmcnt(6) ONLY at K-tile boundary (never 0 in steady state).
// LDS swizzle: chunk' = c ^ (row&7) (write-side pre-swizzled global source,
// read-side XOR; 2-way banks = free).  Same-XCD A-panel block swizzle.
// EPI 0: q(*scale*log2e)/k/v bf16 [win][head][49][32].  EPI 1: fp32 un-windowed.
template<int EPI, int NBY>
__global__ __launch_bounds__(512) void gemm8p(const unsigned short* __restrict__ A,
                                              const unsigned short* __restrict__ B,
                                              const float* __restrict__ bias,
                                              unsigned short* __restrict__ qo,
                                              unsigned short* __restrict__ ko,
                                              unsigned short* __restrict__ vo,
                                              float* __restrict__ out)
{
  constexpr int K = 384;
  __shared__ unsigned short Al[3][256*64];   // 96 KiB
  __shared__ unsigned short Bl[3][128*64];   // 48 KiB
  const int tid = threadIdx.x;
  const int lane = tid & 63, wid = tid >> 6;       // 8 waves
  const int wr = wid >> 1, wc = wid & 1;           // 4M x 2N
  const int l15 = lane & 15, kg = lane >> 4;
  const int xr = l15 & 7;                          // read-side row XOR

  // block swizzle: NBY n-blocks sharing one A-panel stay on one XCD
  const int n = blockIdx.x;
  const int xcd = n & 7, s = n >> 3;
  const int panel = s / NBY, nb = s - panel*NBY;
  const int bx = panel*8 + xcd, by = nb;

  // staging: set s covers rows s*64 + wid*8 + (lane>>3); chunk c=(lane&7)^(lane>>3)
  const int srow = wid*8 + (lane>>3);
  const int schunk = (lane & 7) ^ (lane >> 3);
  const unsigned short* AgS = A + ((size_t)(bx*256 + srow))*K + schunk*8;
  const unsigned short* BgS = B + ((size_t)(by*128 + srow))*K + schunk*8;

#define STAGE_A(buf, kt, ss) ASYNC16(&Al[buf][(ss)*4096 + wid*512], AgS + (size_t)(ss)*64*K + (kt)*64)
#define STAGE_B(buf, kt, ss) ASYNC16(&Bl[buf][(ss)*4096 + wid*512], BgS + (size_t)(ss)*64*K + (kt)*64)

  // fragment read offsets (shorts): row*64 + ((c ^ (row&7))*8), c = ks*4+kg
  int offA[4][2], offB[4][2];
#pragma unroll
  for (int ti=0; ti<4; ++ti){
    int rowA = wr*64 + ti*16 + l15;
    int rowB = wc*64 + ti*16 + l15;
#pragma unroll
    for (int ks=0; ks<2; ++ks){
      offA[ti][ks] = rowA*64 + (((ks*4 + kg) ^ xr)*8);
      offB[ti][ks] = rowB*64 + (((ks*4 + kg) ^ xr)*8);
    }
  }

  f32x4 acc[4][4] = {};

  // prologue: tiles 0,1 -> bufs 0,1 (12 issues); own tile0 landed; publish
  STAGE_A(0,0,0); STAGE_A(0,0,1); STAGE_A(0,0,2); STAGE_A(0,0,3);
  STAGE_B(0,0,0); STAGE_B(0,0,1);
  STAGE_A(1,1,0); STAGE_A(1,1,1); STAGE_A(1,1,2); STAGE_A(1,1,3);
  STAGE_B(1,1,0); STAGE_B(1,1,1);
  asm volatile("s_waitcnt vmcnt(6)\n\ts_barrier" ::: "memory");

#pragma unroll
  for (int t = 0; t < 6; ++t){
    const int buf = t % 3, nbuf = (t + 2) % 3;
    const unsigned short* Ab = Al[buf];
    const unsigned short* Bb = Bl[buf];

    // ---- phase 0: read af[0,1] + all bfv; stage 3 of tile t+2 ----
    bf16x8 af01[2][2], bfv[4][2];
#pragma unroll
    for (int ti=0; ti<2; ++ti)
#pragma unroll
      for (int ks=0; ks<2; ++ks)
        af01[ti][ks] = *(const bf16x8*)(Ab + offA[ti][ks]);
#pragma unroll
    for (int tj=0; tj<4; ++tj)
#pragma unroll
      for (int ks=0; ks<2; ++ks)
        bfv[tj][ks] = *(const bf16x8*)(Bb + offB[tj][ks]);
    if (t < 4){ STAGE_A(nbuf, t+2, 0); STAGE_A(nbuf, t+2, 1); STAGE_A(nbuf, t+2, 2); }
    asm volatile("s_barrier" ::: "memory");

    __builtin_amdgcn_s_setprio(1);
#pragma unroll
    for (int ti=0; ti<2; ++ti)
#pragma unroll
      for (int tj=0; tj<4; ++tj){
        acc[ti][tj] = __builtin_amdgcn_mfma_f32_16x16x32_bf16(af01[ti][0], bfv[tj][0], acc[ti][tj], 0,0,0);
        acc[ti][tj] = __builtin_amdgcn_mfma_f32_16x16x32_bf16(af01[ti][1], bfv[tj][1], acc[ti][tj], 0,0,0);
      }
    __builtin_amdgcn_s_setprio(0);
    asm volatile("s_barrier" ::: "memory");

    // ---- phase 1: read af[2,3]; stage remaining 3 of tile t+2 ----
    bf16x8 af23[2][2];
#pragma unroll
    for (int ti=0; ti<2; ++ti)
#pragma unroll
      for (int ks=0; ks<2; ++ks)
        af23[ti][ks] = *(const bf16x8*)(Ab + offA[2+ti][ks]);
    if (t < 4){ STAGE_A(nbuf, t+2, 3); STAGE_B(nbuf, t+2, 0); STAGE_B(nbuf, t+2, 1); }
    asm volatile("s_barrier" ::: "memory");

    __builtin_amdgcn_s_setprio(1);
#pragma unroll
    for (int ti=0; ti<2; ++ti)
#pragma unroll
      for (int tj=0; tj<4; ++tj){
        acc[2+ti][tj] = __builtin_amdgcn_mfma_f32_16x16x32_bf16(af23[ti][0], bfv[tj][0], acc[2+ti][tj], 0,0,0);
        acc[2+ti][tj] = __builtin_amdgcn_mfma_f32_16x16x32_bf16(af23[ti][1], bfv[tj][1], acc[2+ti][tj], 0,0,0);
      }
    __builtin_amdgcn_s_setprio(0);

    // K-tile boundary: wait tile t+1 landed (tile t+2's 6 stay in flight)
    if (t < 4)       asm volatile("s_waitcnt vmcnt(6)\n\ts_barrier" ::: "memory");
    else if (t == 4) asm volatile("s_waitcnt vmcnt(0)\n\ts_barrier" ::: "memory");
    // t == 5: done, fall through to epilogue
  }
#undef STAGE_A
#undef STAGE_B

  const int rbase = bx*256 + wr*64 + kg*4;

  if (EPI == 0){
    const int t = by / 3;                          // block-uniform q/k/v select
    unsigned short* __restrict__ Pout = (t==0) ? qo : ((t==1) ? ko : vo);
    // q scale folds softmax 1/sqrt(d) AND log2(e) for exp2-softmax
    const float scale = (t==0) ? (0.17677669529663689f * 1.4426950408889634f) : 1.0f;
    const int cb = (by - t*3)*128 + wc*64;         // col base within 384
    int hoff[4]; float bvs[4];
#pragma unroll
    for (int tj=0; tj<4; ++tj){
      int colt = cb + tj*16;
      hoff[tj] = (colt>>5)*1568 + (colt&31) + l15; // head*49*32 + dd
      bvs[tj] = bias[by*128 + wc*64 + tj*16 + l15] * scale;
    }
#pragma unroll
    for (int ti=0; ti<4; ++ti){
#pragma unroll
      for (int r=0; r<4; ++r){
        int R = rbase + ti*16 + r;
        int win = R / 49, nn = R - win*49;
        size_t rowoff = (size_t)win*18816 + nn*32;
#pragma unroll
        for (int tj=0; tj<4; ++tj)
          Pout[rowoff + hoff[tj]] = f2bf(acc[ti][tj][r]*scale + bvs[tj]);
      }
    }
  } else {
    const int cbs = by*128 + wc*64;                // scalar col base
    float bv[4];
#pragma unroll
    for (int tj=0; tj<4; ++tj) bv[tj] = bias[cbs + tj*16 + l15];
#pragma unroll
    for (int ti=0; ti<4; ++ti){
#pragma unroll
      for (int r=0; r<4; ++r){
        int R = rbase + ti*16 + r;
        int win = R / 49, nn = R - win*49;
        int p = nn / 7, q = nn - p*7;
        int h = (win >> 3) & 7, w = win & 7;
        size_t tok = (size_t)(win >> 6)*3136 + (size_t)((p*8 + h)*56 + q*8 + w);
        float* __restrict__ orow = out + tok*384 + cbs + l15;
#pragma unroll
        for (int tj=0; tj<4; ++tj)
          orow[tj*16] = acc[ti][tj][r] + bv[tj];
      }
    }
  }
}

// ---- windowed attention, swapped-QK^T in-register softmax (R4-proven). ----
__global__ __launch_bounds__(256) void attn_kernel(const unsigned short* __restrict__ q,
                                                   const unsigned short* __restrict__ k,
                                                   const unsigned short* __restrict__ v,
                                                   const float* __restrict__ btab,
                                                   unsigned short* __restrict__ ao)
{
  __shared__ unsigned short P[4][4096];   // per-wave 64x64 bf16, XOR-swizzled
  const int tid = threadIdx.x, lane = tid & 63, wid = tid >> 6;
  const int l15 = lane & 15, kg = lane >> 4;
  const int win = blockIdx.x / 3;
  const int head = (blockIdx.x % 3)*4 + wid;
  const size_t base = ((size_t)win*12 + head)*1568;   // 49*32
  const unsigned short* qb = q + base;
  const unsigned short* kb = k + base;
  const unsigned short* vb = v + base;
  const float* bt = btab + head*4096;

  // V fragments first (independent; latency hides under QK^T + softmax).
  bf16x8 vfk[2][2];
#pragma unroll
  for (int ks=0; ks<2; ++ks)
#pragma unroll
    for (int tjv=0; tjv<2; ++tjv)
#pragma unroll
      for (int e=0; e<8; ++e)
        vfk[ks][tjv][e] = (short)vb[(ks*32 + kg*8 + e)*32 + tjv*16 + l15];

  // S^T C-init = bias fragment (coalesced b128 per frag)
  f32x4 s[4][4];
#pragma unroll
  for (int ti=0; ti<4; ++ti)
#pragma unroll
    for (int tj=0; tj<4; ++tj)
      s[ti][tj] = *(const f32x4*)(bt + ((ti*4 + tj)*64 + lane)*4);

  bf16x8 kf[4], qf[4];
#pragma unroll
  for (int ti=0; ti<4; ++ti) kf[ti] = *(const bf16x8*)(kb + (ti*16+l15)*32 + kg*8);
#pragma unroll
  for (int tj=0; tj<4; ++tj) qf[tj] = *(const bf16x8*)(qb + (tj*16+l15)*32 + kg*8);

  __builtin_amdgcn_s_setprio(1);
#pragma unroll
  for (int ti=0; ti<4; ++ti)
#pragma unroll
    for (int tj=0; tj<4; ++tj)
      s[ti][tj] = __builtin_amdgcn_mfma_f32_16x16x32_bf16(kf[ti], qf[tj], s[ti][tj], 0,0,0);
  __builtin_amdgcn_s_setprio(0);

  // softmax: lane owns 4 q-rows (tj), 16 k-values each in-register.
  float rinv[4];
#pragma unroll
  for (int tj=0; tj<4; ++tj){
    float sum = 0.f;
#pragma unroll
    for (int ti=0; ti<4; ++ti)
#pragma unroll
      for (int r=0; r<4; ++r){
        float e = exp2f(s[ti][tj][r]);
        s[ti][tj][r] = e;
        sum += e;
      }
    sum += __shfl_xor(sum, 16);
    sum += __shfl_xor(sum, 32);
    rinv[tj] = __builtin_amdgcn_rcpf(sum);
  }

  // pack P (x rinv) as bf16 k-pairs -> swizzled LDS [q=64][k=64]
  unsigned short* Pl = P[wid];
  const unsigned swz = (unsigned)((l15 & 7) << 4);
#pragma unroll
  for (int tj=0; tj<4; ++tj){
    const float rv = rinv[tj];
    const unsigned rowb = (unsigned)((tj*16 + l15)*128);
#pragma unroll
    for (int ti=0; ti<4; ++ti){
      uint2 d;
      d.x = cvt_pk_bf16(s[ti][tj][0]*rv, s[ti][tj][1]*rv);
      d.y = cvt_pk_bf16(s[ti][tj][2]*rv, s[ti][tj][3]*rv);
      unsigned boff = (rowb + (unsigned)(ti*32 + kg*8)) ^ swz;
      *(uint2*)((char*)Pl + boff) = d;
    }
  }

  // O = P @ V
  f32x4 o[4][2] = {};
#pragma unroll
  for (int oti=0; oti<4; ++oti){
    bf16x8 pa[2];
#pragma unroll
    for (int ks=0; ks<2; ++ks){
      unsigned boff = ((unsigned)((oti*16+l15)*128 + ks*64 + kg*16)) ^ swz;
      pa[ks] = *(const bf16x8*)((char*)Pl + boff);
    }
    __builtin_amdgcn_s_setprio(1);
#pragma unroll
    for (int tjv=0; tjv<2; ++tjv){
      o[oti][tjv] = __builtin_amdgcn_mfma_f32_16x16x32_bf16(pa[0], vfk[0][tjv], o[oti][tjv], 0,0,0);
      o[oti][tjv] = __builtin_amdgcn_mfma_f32_16x16x32_bf16(pa[1], vfk[1][tjv], o[oti][tjv], 0,0,0);
    }
    __builtin_amdgcn_s_setprio(0);
  }

  // store rows < 49 (rinv already folded into P)
#pragma unroll
  for (int oti=0; oti<4; ++oti)
#pragma unroll
    for (int r=0; r<4; ++r){
      int row = oti*16 + kg*4 + r;
      if (row < 49){
        unsigned short* op = ao + ((size_t)win*49 + row)*384 + head*32 + l15;
        op[0]  = (unsigned short)cvt_pk_bf16(o[oti][0][r], o[oti][0][r]);
        op[16] = (unsigned short)cvt_pk_bf16(o[oti][1][r], o[oti][1][r]);
      }
    }
}

extern "C" void kernel_launch(void* const* d_in, const int* in_sizes, int n_in,
                              void* d_out, int out_size, void* d_ws, size_t ws_size,
                              hipStream_t stream)
{
  const float* x       = (const float*)d_in[0];   // 32*56*56*384
  const float* w_qkv   = (const float*)d_in[1];   // 1152*384
  const float* b_qkv   = (const float*)d_in[2];   // 1152
  const float* rel_pos = (const float*)d_in[3];   // 12*169
  const float* w_out   = (const float*)d_in[4];   // 384*384
  const float* b_out   = (const float*)d_in[5];   // 384
  float* out = (float*)d_out;                     // 100352*384

  char* ws = (char*)d_ws;
  unsigned short* wqb = (unsigned short*)ws;                  // 884736 B
  unsigned short* wob = (unsigned short*)(ws + 884736);       // 294912 B
  float* btab         = (float*)(ws + 884736 + 294912);       // 196608 B
  unsigned short* qws = (unsigned short*)(ws + 1376256);      // 38535168 elems
  unsigned short* kws = qws + 38535168;
  unsigned short* vws = kws + 38535168;
  unsigned short* xb  = vws + 38535168;   // x_bf during GEMM1, attn-out after
  unsigned short* ao  = xb;               // total ws ~309.7 MB

  convert_x_kernel<<<dim3(37632), dim3(256), 0, stream>>>(x, xb);
  convert_w_kernel<<<dim3(576),   dim3(256), 0, stream>>>(w_qkv, w_out, wqb, wob);
  build_btab<<<dim3(48), dim3(256), 0, stream>>>(rel_pos, btab);
  gemm8p<0,9><<<dim3(3528), dim3(512), 0, stream>>>(xb, wqb, b_qkv, qws, kws, vws, nullptr);
  attn_kernel<<<dim3(6144), dim3(256), 0, stream>>>(qws, kws, vws, btab, ao);
  gemm8p<1,3><<<dim3(1176), dim3(512), 0, stream>>>(ao, wob, b_out, nullptr, nullptr, nullptr, out);
}

// Round 11
// 315.381 us; speedup vs baseline: 1.0362x; 1.0362x over previous
//
#include <hip/hip_runtime.h>

typedef __attribute__((ext_vector_type(8))) short bf16x8;
typedef __attribute__((ext_vector_type(4))) float f32x4;

__device__ __forceinline__ unsigned short f2bf(float f){
  unsigned u = __builtin_bit_cast(unsigned, f);
  u += 0x7fffu + ((u >> 16) & 1u);
  return (unsigned short)(u >> 16);
}

__device__ __forceinline__ unsigned cvt_pk_bf16(float lo, float hi){
  unsigned r;
  asm("v_cvt_pk_bf16_f32 %0, %1, %2" : "=v"(r) : "v"(lo), "v"(hi));
  return r;
}

#define ASYNC16(ldsp, gp) __builtin_amdgcn_global_load_lds( \
    (const __attribute__((address_space(1))) unsigned int*)(gp), \
    (__attribute__((address_space(3))) unsigned int*)(ldsp), 16, 0, 0)

// ---- convert x (fp32 [b,56,56,384]) -> bf16 window-ordered [win*49+n][384] ----
__global__ __launch_bounds__(256) void convert_x_kernel(const float* __restrict__ x,
                                                        unsigned short* __restrict__ xb){
  int idx = blockIdx.x*256 + threadIdx.x;          // 100352*96 threads, 4 ch each
  int token = idx / 96, j = idx - token*96;
  int b = token / 3136, rem = token - b*3136;
  int rr = rem / 56, cp = rem - rr*56;
  int p = rr >> 3, h = rr & 7, q = cp >> 3, w = cp & 7;
  int orow = ((b*8 + h)*8 + w)*49 + p*7 + q;
  float4 v = *(const float4*)(x + (size_t)idx*4);
  ushort4 o;
  o.x = f2bf(v.x); o.y = f2bf(v.y); o.z = f2bf(v.z); o.w = f2bf(v.w);
  *(ushort4*)(xb + (size_t)orow*384 + j*4) = o;
}

// ---- convert weights fp32 -> bf16 ----
__global__ __launch_bounds__(256) void convert_w_kernel(const float* __restrict__ wq,
                                                        const float* __restrict__ wo,
                                                        unsigned short* __restrict__ wqb,
                                                        unsigned short* __restrict__ wob){
  int idx = blockIdx.x*256 + threadIdx.x;          // 147456 threads
  if (idx < 110592){
    float4 v = *(const float4*)(wq + (size_t)idx*4);
    ushort4 o; o.x=f2bf(v.x); o.y=f2bf(v.y); o.z=f2bf(v.z); o.w=f2bf(v.w);
    *(ushort4*)(wqb + (size_t)idx*4) = o;
  } else {
    int k = idx - 110592;
    float4 v = *(const float4*)(wo + (size_t)k*4);
    ushort4 o; o.x=f2bf(v.x); o.y=f2bf(v.y); o.z=f2bf(v.z); o.w=f2bf(v.w);
    *(ushort4*)(wob + (size_t)k*4) = o;
  }
}

// ---- bias table, FRAGMENT-major: btab[head][fi=ti*4+tj][lane][r] (f32),
// log2(e)-pre-scaled; -inf for k>=49 (mask); 0 for q>=49. Coalesced b128 loads. ----
__global__ __launch_bounds__(256) void build_btab(const float* __restrict__ rel_pos,
                                                  float* __restrict__ btab){
  int idx = blockIdx.x*256 + threadIdx.x;          // 12288 threads
  int head = idx >> 10, rem = idx & 1023;
  int fi = rem >> 6, lane = rem & 63;
  int ti = fi >> 2, tj = fi & 3;
  int qq = tj*16 + (lane & 15);
  int kb = ti*16 + (lane >> 4)*4;
  float4 v; float* vp = (float*)&v;
#pragma unroll
  for (int r=0; r<4; ++r){
    int kk = kb + r;
    float val;
    if (kk >= 49) val = -__builtin_inff();
    else if (qq >= 49) val = 0.f;
    else {
      int ip = qq/7, iq = qq - ip*7, jp = kk/7, jq = kk - jp*7;
      val = rel_pos[head*169 + (ip-jp+6)*13 + (iq-jq+6)] * 1.4426950408889634f;
    }
    vp[r] = val;
  }
  *(float4*)(btab + (size_t)idx*4) = v;
}

// ---- 256x128 tile bf16 GEMM (R9-proven best): C = A @ B^T + bias, K=384.
// A,B via ASYNC16 into XOR-k-chunk-swizzled LDS (0 conflicts); triple-buffered
// single-barrier pipeline, counted vmcnt(6). Same-XCD A-panel block swizzle.
// EPI 0: q(*scale*log2e)/k/v bf16 [win][head][49][32].  EPI 1: fp32 un-windowed.
template<int EPI, int NBY>
__global__ __launch_bounds__(256) void gemm256(const unsigned short* __restrict__ A,
                                               const unsigned short* __restrict__ B,
                                               const float* __restrict__ bias,
                                               unsigned short* __restrict__ qo,
                                               unsigned short* __restrict__ ko,
                                               unsigned short* __restrict__ vo,
                                               float* __restrict__ out)
{
  constexpr int K = 384;
  constexpr int NT = 12;                    // K/32
  __shared__ unsigned short Al[3][256*32];  // 48 KiB
  __shared__ unsigned short Bl[3][128*32];  // 24 KiB
  const int tid = threadIdx.x;
  const int lane = tid & 63, wid = tid >> 6;
  const int wr = wid >> 1, wc = wid & 1;
  const int l15 = lane & 15, kg = lane >> 4;
  const int swz = (l15 >> 1) & 3;                       // read-side chunk XOR
  const int cswz = (tid & 3) ^ ((tid >> 3) & 3);        // source pre-swizzle

  // block swizzle: NBY n-blocks sharing one A-panel stay on one XCD
  const int n = blockIdx.x;
  const int xcd = n & 7, s = n >> 3;
  const int panel = s / NBY, nb = s - panel*NBY;
  const int bx = panel*8 + xcd, by = nb;

  const unsigned short* Ag = A + ((size_t)bx*256 + (tid>>2))*K + cswz*8;
  const unsigned short* Bg = B + ((size_t)(by*128 + (tid>>2)))*K + cswz*8;

  f32x4 acc[8][4] = {};

#define STAGE(buf, kt) do { \
    ASYNC16(&Al[buf][wid*512],        Ag + (kt)*32); \
    ASYNC16(&Al[buf][wid*512 + 2048], Ag + (size_t)64*K  + (kt)*32); \
    ASYNC16(&Al[buf][wid*512 + 4096], Ag + (size_t)128*K + (kt)*32); \
    ASYNC16(&Al[buf][wid*512 + 6144], Ag + (size_t)192*K + (kt)*32); \
    ASYNC16(&Bl[buf][wid*512],        Bg + (kt)*32); \
    ASYNC16(&Bl[buf][wid*512 + 2048], Bg + (size_t)64*K  + (kt)*32); \
  } while(0)

  STAGE(0,0); STAGE(1,1);                   // 12 own loads in flight

#pragma unroll
  for (int t = 0; t < NT; ++t){
    if (t < NT-1) asm volatile("s_waitcnt vmcnt(6)\n\ts_barrier" ::: "memory");
    else          asm volatile("s_waitcnt vmcnt(0)\n\ts_barrier" ::: "memory");

    if (t + 2 < NT) STAGE((t+2)%3, t+2);

    const unsigned short* Ab = Al[t % 3];
    const unsigned short* Bb = Bl[t % 3];
    bf16x8 af[8], bfv[4];
#pragma unroll
    for (int ti=0; ti<8; ++ti)
      af[ti] = *(const bf16x8*)(Ab + (wr*128 + ti*16 + l15)*32 + (kg ^ swz)*8);
#pragma unroll
    for (int tj=0; tj<4; ++tj)
      bfv[tj] = *(const bf16x8*)(Bb + (wc*64 + tj*16 + l15)*32 + (kg ^ swz)*8);

    __builtin_amdgcn_s_setprio(1);
#pragma unroll
    for (int ti=0; ti<8; ++ti)
#pragma unroll
      for (int tj=0; tj<4; ++tj)
        acc[ti][tj] = __builtin_amdgcn_mfma_f32_16x16x32_bf16(af[ti], bfv[tj], acc[ti][tj], 0,0,0);
    __builtin_amdgcn_s_setprio(0);
  }
#undef STAGE

  const int rbase = bx*256 + wr*128 + kg*4;

  if (EPI == 0){
    const int t = by / 3;                          // block-uniform q/k/v select
    unsigned short* __restrict__ Pout = (t==0) ? qo : ((t==1) ? ko : vo);
    // q scale folds softmax 1/sqrt(d) AND log2(e) for exp2-softmax
    const float scale = (t==0) ? (0.17677669529663689f * 1.4426950408889634f) : 1.0f;
    const int cb = (by - t*3)*128 + wc*64;         // col base within 384
    int hoff[4]; float bvs[4];
#pragma unroll
    for (int tj=0; tj<4; ++tj){
      int colt = cb + tj*16;
      hoff[tj] = (colt>>5)*1568 + (colt&31) + l15; // head*49*32 + dd
      bvs[tj] = bias[by*128 + wc*64 + tj*16 + l15] * scale;
    }
#pragma unroll
    for (int ti=0; ti<8; ++ti){
#pragma unroll
      for (int r=0; r<4; ++r){
        int R = rbase + ti*16 + r;
        int win = R / 49, nn = R - win*49;
        size_t rowoff = (size_t)win*18816 + nn*32;
#pragma unroll
        for (int tj=0; tj<4; ++tj)
          Pout[rowoff + hoff[tj]] = f2bf(acc[ti][tj][r]*scale + bvs[tj]);
      }
    }
  } else {
    const int cbs = by*128 + wc*64;                // scalar col base
    float bv[4];
#pragma unroll
    for (int tj=0; tj<4; ++tj) bv[tj] = bias[cbs + tj*16 + l15];
#pragma unroll
    for (int ti=0; ti<8; ++ti){
#pragma unroll
      for (int r=0; r<4; ++r){
        int R = rbase + ti*16 + r;
        int win = R / 49, nn = R - win*49;
        int p = nn / 7, q = nn - p*7;
        int h = (win >> 3) & 7, w = win & 7;
        size_t tok = (size_t)(win >> 6)*3136 + (size_t)((p*8 + h)*56 + q*8 + w);
        float* __restrict__ orow = out + tok*384 + cbs + l15;
#pragma unroll
        for (int tj=0; tj<4; ++tj)
          orow[tj*16] = acc[ti][tj][r] + bv[tj];
      }
    }
  }
}

// ---- windowed attention, swapped-QK^T in-register softmax.
// NEW: 2 windows per wave with cross-window prefetch -- V/q/k fragments of
// window w+1 are issued right after window w's QK^T, hiding their ~L3 latency
// under w's softmax + P-pack + PV. btab C-init re-read per window (L1-hot,
// same head). s[] reused; P-LDS wave-private (compiler orders the WAR dep). ----
#define ATTN_QK(KF, QF) do { \
  _Pragma("unroll") \
  for (int ti=0; ti<4; ++ti) \
    _Pragma("unroll") \
    for (int tj=0; tj<4; ++tj) \
      s[ti][tj] = *(const f32x4*)(bt + ((ti*4 + tj)*64 + lane)*4); \
  __builtin_amdgcn_s_setprio(1); \
  _Pragma("unroll") \
  for (int ti=0; ti<4; ++ti) \
    _Pragma("unroll") \
    for (int tj=0; tj<4; ++tj) \
      s[ti][tj] = __builtin_amdgcn_mfma_f32_16x16x32_bf16(KF[ti], QF[tj], s[ti][tj], 0,0,0); \
  __builtin_amdgcn_s_setprio(0); \
} while(0)

#define ATTN_TAIL(VV, WADD) do { \
  float rinv[4]; \
  _Pragma("unroll") \
  for (int tj=0; tj<4; ++tj){ \
    float sum = 0.f; \
    _Pragma("unroll") \
    for (int ti=0; ti<4; ++ti) \
      _Pragma("unroll") \
      for (int r=0; r<4; ++r){ \
        float e = exp2f(s[ti][tj][r]); \
        s[ti][tj][r] = e; \
        sum += e; \
      } \
    sum += __shfl_xor(sum, 16); \
    sum += __shfl_xor(sum, 32); \
    rinv[tj] = __builtin_amdgcn_rcpf(sum); \
  } \
  _Pragma("unroll") \
  for (int tj=0; tj<4; ++tj){ \
    const float rv = rinv[tj]; \
    const unsigned rowb = (unsigned)((tj*16 + l15)*128); \
    _Pragma("unroll") \
    for (int ti=0; ti<4; ++ti){ \
      uint2 d; \
      d.x = cvt_pk_bf16(s[ti][tj][0]*rv, s[ti][tj][1]*rv); \
      d.y = cvt_pk_bf16(s[ti][tj][2]*rv, s[ti][tj][3]*rv); \
      unsigned boff = (rowb + (unsigned)(ti*32 + kg*8)) ^ swzP; \
      *(uint2*)((char*)Pl + boff) = d; \
    } \
  } \
  f32x4 o[4][2] = {}; \
  _Pragma("unroll") \
  for (int oti=0; oti<4; ++oti){ \
    bf16x8 pa[2]; \
    _Pragma("unroll") \
    for (int ks=0; ks<2; ++ks){ \
      unsigned boff = ((unsigned)((oti*16+l15)*128 + ks*64 + kg*16)) ^ swzP; \
      pa[ks] = *(const bf16x8*)((char*)Pl + boff); \
    } \
    __builtin_amdgcn_s_setprio(1); \
    _Pragma("unroll") \
    for (int tjv=0; tjv<2; ++tjv){ \
      o[oti][tjv] = __builtin_amdgcn_mfma_f32_16x16x32_bf16(pa[0], VV[0][tjv], o[oti][tjv], 0,0,0); \
      o[oti][tjv] = __builtin_amdgcn_mfma_f32_16x16x32_bf16(pa[1], VV[1][tjv], o[oti][tjv], 0,0,0); \
    } \
    __builtin_amdgcn_s_setprio(0); \
  } \
  _Pragma("unroll") \
  for (int oti=0; oti<4; ++oti) \
    _Pragma("unroll") \
    for (int r=0; r<4; ++r){ \
      int row = oti*16 + kg*4 + r; \
      if (row < 49){ \
        unsigned short* op = ao + ((size_t)(win0 + (WADD))*49 + row)*384 + head*32 + l15; \
        op[0]  = (unsigned short)cvt_pk_bf16(o[oti][0][r], o[oti][0][r]); \
        op[16] = (unsigned short)cvt_pk_bf16(o[oti][1][r], o[oti][1][r]); \
      } \
    } \
} while(0)

__global__ __launch_bounds__(256) void attn_kernel(const unsigned short* __restrict__ q,
                                                   const unsigned short* __restrict__ k,
                                                   const unsigned short* __restrict__ v,
                                                   const float* __restrict__ btab,
                                                   unsigned short* __restrict__ ao)
{
  __shared__ unsigned short P[4][4096];   // per-wave 64x64 bf16, XOR-swizzled
  const int tid = threadIdx.x, lane = tid & 63, wid = tid >> 6;
  const int l15 = lane & 15, kg = lane >> 4;
  const int head = (blockIdx.x % 3)*4 + wid;
  const int win0 = (blockIdx.x / 3)*2;           // 1024 pairs x 3 = 3072 blocks
  const size_t base0 = ((size_t)win0*12 + head)*1568;   // 49*32
  const unsigned short* qb = q + base0;
  const unsigned short* kb = k + base0;
  const unsigned short* vb = v + base0;
  const float* bt = btab + head*4096;
  unsigned short* Pl = P[wid];
  const unsigned swzP = (unsigned)((l15 & 7) << 4);
  constexpr int WOFF = 12*1568;                  // next window, same head

  f32x4 s[4][4];
  bf16x8 vA[2][2], vB[2][2], kfA[4], qfA[4], kfB[4], qfB[4];

  // ---- window 0 loads ----
#pragma unroll
  for (int ks=0; ks<2; ++ks)
#pragma unroll
    for (int tjv=0; tjv<2; ++tjv)
#pragma unroll
      for (int e=0; e<8; ++e)
        vA[ks][tjv][e] = (short)vb[(ks*32 + kg*8 + e)*32 + tjv*16 + l15];
#pragma unroll
  for (int i=0; i<4; ++i){
    kfA[i] = *(const bf16x8*)(kb + (i*16+l15)*32 + kg*8);
    qfA[i] = *(const bf16x8*)(qb + (i*16+l15)*32 + kg*8);
  }

  // ---- window 0: QK^T ----
  ATTN_QK(kfA, qfA);

  // ---- prefetch window 1 (latency hides under softmax+pack+PV of window 0) ----
#pragma unroll
  for (int ks=0; ks<2; ++ks)
#pragma unroll
    for (int tjv=0; tjv<2; ++tjv)
#pragma unroll
      for (int e=0; e<8; ++e)
        vB[ks][tjv][e] = (short)vb[WOFF + (ks*32 + kg*8 + e)*32 + tjv*16 + l15];
#pragma unroll
  for (int i=0; i<4; ++i){
    kfB[i] = *(const bf16x8*)(kb + WOFF + (i*16+l15)*32 + kg*8);
    qfB[i] = *(const bf16x8*)(qb + WOFF + (i*16+l15)*32 + kg*8);
  }

  // ---- window 0: softmax + P-pack + PV + store ----
  ATTN_TAIL(vA, 0);

  // ---- window 1 ----
  ATTN_QK(kfB, qfB);
  ATTN_TAIL(vB, 1);
}

extern "C" void kernel_launch(void* const* d_in, const int* in_sizes, int n_in,
                              void* d_out, int out_size, void* d_ws, size_t ws_size,
                              hipStream_t stream)
{
  const float* x       = (const float*)d_in[0];   // 32*56*56*384
  const float* w_qkv   = (const float*)d_in[1];   // 1152*384
  const float* b_qkv   = (const float*)d_in[2];   // 1152
  const float* rel_pos = (const float*)d_in[3];   // 12*169
  const float* w_out   = (const float*)d_in[4];   // 384*384
  const float* b_out   = (const float*)d_in[5];   // 384
  float* out = (float*)d_out;                     // 100352*384

  char* ws = (char*)d_ws;
  unsigned short* wqb = (unsigned short*)ws;                  // 884736 B
  unsigned short* wob = (unsigned short*)(ws + 884736);       // 294912 B
  float* btab         = (float*)(ws + 884736 + 294912);       // 196608 B
  unsigned short* qws = (unsigned short*)(ws + 1376256);      // 38535168 elems
  unsigned short* kws = qws + 38535168;
  unsigned short* vws = kws + 38535168;
  unsigned short* xb  = vws + 38535168;   // x_bf during GEMM1, attn-out after
  unsigned short* ao  = xb;               // total ws ~309.7 MB

  convert_x_kernel<<<dim3(37632), dim3(256), 0, stream>>>(x, xb);
  convert_w_kernel<<<dim3(576),   dim3(256), 0, stream>>>(w_qkv, w_out, wqb, wob);
  build_btab<<<dim3(48), dim3(256), 0, stream>>>(rel_pos, btab);
  gemm256<0,9><<<dim3(3528), dim3(256), 0, stream>>>(xb, wqb, b_qkv, qws, kws, vws, nullptr);
  attn_kernel<<<dim3(3072), dim3(256), 0, stream>>>(qws, kws, vws, btab, ao);
  gemm256<1,3><<<dim3(1176), dim3(256), 0, stream>>>(ao, wob, b_out, nullptr, nullptr, nullptr, out);
}

// Round 12
// 303.238 us; speedup vs baseline: 1.0777x; 1.0400x over previous
//
#include <hip/hip_runtime.h>

typedef __attribute__((ext_vector_type(8))) short bf16x8;
typedef __attribute__((ext_vector_type(4))) float f32x4;

__device__ __forceinline__ unsigned short f2bf(float f){
  unsigned u = __builtin_bit_cast(unsigned, f);
  u += 0x7fffu + ((u >> 16) & 1u);
  return (unsigned short)(u >> 16);
}

__device__ __forceinline__ unsigned cvt_pk_bf16(float lo, float hi){
  unsigned r;
  asm("v_cvt_pk_bf16_f32 %0, %1, %2" : "=v"(r) : "v"(lo), "v"(hi));
  return r;
}

#define ASYNC16(ldsp, gp) __builtin_amdgcn_global_load_lds( \
    (const __attribute__((address_space(1))) unsigned int*)(gp), \
    (__attribute__((address_space(3))) unsigned int*)(ldsp), 16, 0, 0)

// ---- fused prep: x fp32 -> bf16 window-ordered; weights -> bf16; bias table.
// blockIdx ranges: [0,37632) convert x; [37632,38208) convert weights;
// [38208,38256) build btab (fragment-major, log2e-scaled, -inf mask k>=49). ----
__global__ __launch_bounds__(256) void prep_kernel(const float* __restrict__ x,
                                                   const float* __restrict__ wq,
                                                   const float* __restrict__ wo,
                                                   const float* __restrict__ rel_pos,
                                                   unsigned short* __restrict__ xb,
                                                   unsigned short* __restrict__ wqb,
                                                   unsigned short* __restrict__ wob,
                                                   float* __restrict__ btab){
  const int bid = blockIdx.x;
  if (bid < 37632){
    int idx = bid*256 + threadIdx.x;               // 100352*96 threads, 4 ch each
    int token = idx / 96, j = idx - token*96;
    int b = token / 3136, rem = token - b*3136;
    int rr = rem / 56, cp = rem - rr*56;
    int p = rr >> 3, h = rr & 7, q = cp >> 3, w = cp & 7;
    int orow = ((b*8 + h)*8 + w)*49 + p*7 + q;
    float4 v = *(const float4*)(x + (size_t)idx*4);
    ushort4 o;
    o.x = f2bf(v.x); o.y = f2bf(v.y); o.z = f2bf(v.z); o.w = f2bf(v.w);
    *(ushort4*)(xb + (size_t)orow*384 + j*4) = o;
  } else if (bid < 38208){
    int idx = (bid - 37632)*256 + threadIdx.x;     // 147456 threads
    if (idx < 110592){
      float4 v = *(const float4*)(wq + (size_t)idx*4);
      ushort4 o; o.x=f2bf(v.x); o.y=f2bf(v.y); o.z=f2bf(v.z); o.w=f2bf(v.w);
      *(ushort4*)(wqb + (size_t)idx*4) = o;
    } else {
      int k = idx - 110592;
      float4 v = *(const float4*)(wo + (size_t)k*4);
      ushort4 o; o.x=f2bf(v.x); o.y=f2bf(v.y); o.z=f2bf(v.z); o.w=f2bf(v.w);
      *(ushort4*)(wob + (size_t)k*4) = o;
    }
  } else {
    int idx = (bid - 38208)*256 + threadIdx.x;     // 12288 threads
    int head = idx >> 10, rem = idx & 1023;
    int fi = rem >> 6, lane = rem & 63;
    int ti = fi >> 2, tj = fi & 3;
    int qq = tj*16 + (lane & 15);
    int kb = ti*16 + (lane >> 4)*4;
    float4 v; float* vp = (float*)&v;
#pragma unroll
    for (int r=0; r<4; ++r){
      int kk = kb + r;
      float val;
      if (kk >= 49) val = -__builtin_inff();
      else if (qq >= 49) val = 0.f;
      else {
        int ip = qq/7, iq = qq - ip*7, jp = kk/7, jq = kk - jp*7;
        val = rel_pos[head*169 + (ip-jp+6)*13 + (iq-jq+6)] * 1.4426950408889634f;
      }
      vp[r] = val;
    }
    *(float4*)(btab + (size_t)idx*4) = v;
  }
}

// ---- 256x128 tile bf16 GEMM (R9-proven best): C = A @ B^T + bias, K=384.
// A,B via ASYNC16 into XOR-k-chunk-swizzled LDS (0 conflicts); triple-buffered
// single-barrier pipeline, counted vmcnt(6). Same-XCD A-panel block swizzle.
// EPI 0: q(*scale*log2e)/k/v bf16 [win][head][49][32].  EPI 1: fp32 un-windowed.
template<int EPI, int NBY>
__global__ __launch_bounds__(256) void gemm256(const unsigned short* __restrict__ A,
                                               const unsigned short* __restrict__ B,
                                               const float* __restrict__ bias,
                                               unsigned short* __restrict__ qo,
                                               unsigned short* __restrict__ ko,
                                               unsigned short* __restrict__ vo,
                                               float* __restrict__ out)
{
  constexpr int K = 384;
  constexpr int NT = 12;                    // K/32
  __shared__ unsigned short Al[3][256*32];  // 48 KiB
  __shared__ unsigned short Bl[3][128*32];  // 24 KiB
  const int tid = threadIdx.x;
  const int lane = tid & 63, wid = tid >> 6;
  const int wr = wid >> 1, wc = wid & 1;
  const int l15 = lane & 15, kg = lane >> 4;
  const int swz = (l15 >> 1) & 3;                       // read-side chunk XOR
  const int cswz = (tid & 3) ^ ((tid >> 3) & 3);        // source pre-swizzle

  // block swizzle: NBY n-blocks sharing one A-panel stay on one XCD
  const int n = blockIdx.x;
  const int xcd = n & 7, s = n >> 3;
  const int panel = s / NBY, nb = s - panel*NBY;
  const int bx = panel*8 + xcd, by = nb;

  const unsigned short* Ag = A + ((size_t)bx*256 + (tid>>2))*K + cswz*8;
  const unsigned short* Bg = B + ((size_t)(by*128 + (tid>>2)))*K + cswz*8;

  f32x4 acc[8][4] = {};

#define STAGE(buf, kt) do { \
    ASYNC16(&Al[buf][wid*512],        Ag + (kt)*32); \
    ASYNC16(&Al[buf][wid*512 + 2048], Ag + (size_t)64*K  + (kt)*32); \
    ASYNC16(&Al[buf][wid*512 + 4096], Ag + (size_t)128*K + (kt)*32); \
    ASYNC16(&Al[buf][wid*512 + 6144], Ag + (size_t)192*K + (kt)*32); \
    ASYNC16(&Bl[buf][wid*512],        Bg + (kt)*32); \
    ASYNC16(&Bl[buf][wid*512 + 2048], Bg + (size_t)64*K  + (kt)*32); \
  } while(0)

  STAGE(0,0); STAGE(1,1);                   // 12 own loads in flight

#pragma unroll
  for (int t = 0; t < NT; ++t){
    if (t < NT-1) asm volatile("s_waitcnt vmcnt(6)\n\ts_barrier" ::: "memory");
    else          asm volatile("s_waitcnt vmcnt(0)\n\ts_barrier" ::: "memory");

    if (t + 2 < NT) STAGE((t+2)%3, t+2);

    const unsigned short* Ab = Al[t % 3];
    const unsigned short* Bb = Bl[t % 3];
    bf16x8 af[8], bfv[4];
#pragma unroll
    for (int ti=0; ti<8; ++ti)
      af[ti] = *(const bf16x8*)(Ab + (wr*128 + ti*16 + l15)*32 + (kg ^ swz)*8);
#pragma unroll
    for (int tj=0; tj<4; ++tj)
      bfv[tj] = *(const bf16x8*)(Bb + (wc*64 + tj*16 + l15)*32 + (kg ^ swz)*8);

    __builtin_amdgcn_s_setprio(1);
#pragma unroll
    for (int ti=0; ti<8; ++ti)
#pragma unroll
      for (int tj=0; tj<4; ++tj)
        acc[ti][tj] = __builtin_amdgcn_mfma_f32_16x16x32_bf16(af[ti], bfv[tj], acc[ti][tj], 0,0,0);
    __builtin_amdgcn_s_setprio(0);
  }
#undef STAGE

  const int rbase = bx*256 + wr*128 + kg*4;

  if (EPI == 0){
    const int t = by / 3;                          // block-uniform q/k/v select
    unsigned short* __restrict__ Pout = (t==0) ? qo : ((t==1) ? ko : vo);
    // q scale folds softmax 1/sqrt(d) AND log2(e) for exp2-softmax
    const float scale = (t==0) ? (0.17677669529663689f * 1.4426950408889634f) : 1.0f;
    const int cb = (by - t*3)*128 + wc*64;         // col base within 384
    int hoff[4]; float bvs[4];
#pragma unroll
    for (int tj=0; tj<4; ++tj){
      int colt = cb + tj*16;
      hoff[tj] = (colt>>5)*1568 + (colt&31) + l15; // head*49*32 + dd
      bvs[tj] = bias[by*128 + wc*64 + tj*16 + l15] * scale;
    }
#pragma unroll
    for (int ti=0; ti<8; ++ti){
#pragma unroll
      for (int r=0; r<4; ++r){
        int R = rbase + ti*16 + r;
        int win = R / 49, nn = R - win*49;
        size_t rowoff = (size_t)win*18816 + nn*32;
#pragma unroll
        for (int tj=0; tj<4; ++tj)
          Pout[rowoff + hoff[tj]] = f2bf(acc[ti][tj][r]*scale + bvs[tj]);
      }
    }
  } else {
    const int cbs = by*128 + wc*64;                // scalar col base
    float bv[4];
#pragma unroll
    for (int tj=0; tj<4; ++tj) bv[tj] = bias[cbs + tj*16 + l15];
#pragma unroll
    for (int ti=0; ti<8; ++ti){
#pragma unroll
      for (int r=0; r<4; ++r){
        int R = rbase + ti*16 + r;
        int win = R / 49, nn = R - win*49;
        int p = nn / 7, q = nn - p*7;
        int h = (win >> 3) & 7, w = win & 7;
        size_t tok = (size_t)(win >> 6)*3136 + (size_t)((p*8 + h)*56 + q*8 + w);
        float* __restrict__ orow = out + tok*384 + cbs + l15;
#pragma unroll
        for (int tj=0; tj<4; ++tj)
          orow[tj*16] = acc[ti][tj][r] + bv[tj];
      }
    }
  }
}

// ---- windowed attention, swapped-QK^T in-register softmax (R9-proven form:
// 1 wave per (window, head); V/q/k fragments loaded up-front; bias C-init from
// fragment-major btab; exp2 softmax fully in-register; P*rinv via cvt_pk ->
// swizzled LDS; PV from LDS + V fragments. ----
__global__ __launch_bounds__(256) void attn_kernel(const unsigned short* __restrict__ q,
                                                   const unsigned short* __restrict__ k,
                                                   const unsigned short* __restrict__ v,
                                                   const float* __restrict__ btab,
                                                   unsigned short* __restrict__ ao)
{
  __shared__ unsigned short P[4][4096];   // per-wave 64x64 bf16, XOR-swizzled
  const int tid = threadIdx.x, lane = tid & 63, wid = tid >> 6;
  const int l15 = lane & 15, kg = lane >> 4;
  const int win = blockIdx.x / 3;
  const int head = (blockIdx.x % 3)*4 + wid;
  const size_t base = ((size_t)win*12 + head)*1568;   // 49*32
  const unsigned short* qb = q + base;
  const unsigned short* kb = k + base;
  const unsigned short* vb = v + base;
  const float* bt = btab + head*4096;

  // V fragments first (independent; latency hides under QK^T + softmax).
  bf16x8 vfk[2][2];
#pragma unroll
  for (int ks=0; ks<2; ++ks)
#pragma unroll
    for (int tjv=0; tjv<2; ++tjv)
#pragma unroll
      for (int e=0; e<8; ++e)
        vfk[ks][tjv][e] = (short)vb[(ks*32 + kg*8 + e)*32 + tjv*16 + l15];

  // S^T C-init = bias fragment (coalesced b128 per frag)
  f32x4 s[4][4];
#pragma unroll
  for (int ti=0; ti<4; ++ti)
#pragma unroll
    for (int tj=0; tj<4; ++tj)
      s[ti][tj] = *(const f32x4*)(bt + ((ti*4 + tj)*64 + lane)*4);

  bf16x8 kf[4], qf[4];
#pragma unroll
  for (int ti=0; ti<4; ++ti) kf[ti] = *(const bf16x8*)(kb + (ti*16+l15)*32 + kg*8);
#pragma unroll
  for (int tj=0; tj<4; ++tj) qf[tj] = *(const bf16x8*)(qb + (tj*16+l15)*32 + kg*8);

  __builtin_amdgcn_s_setprio(1);
#pragma unroll
  for (int ti=0; ti<4; ++ti)
#pragma unroll
    for (int tj=0; tj<4; ++tj)
      s[ti][tj] = __builtin_amdgcn_mfma_f32_16x16x32_bf16(kf[ti], qf[tj], s[ti][tj], 0,0,0);
  __builtin_amdgcn_s_setprio(0);

  // softmax: lane owns 4 q-rows (tj), 16 k-values each in-register.
  float rinv[4];
#pragma unroll
  for (int tj=0; tj<4; ++tj){
    float sum = 0.f;
#pragma unroll
    for (int ti=0; ti<4; ++ti)
#pragma unroll
      for (int r=0; r<4; ++r){
        float e = exp2f(s[ti][tj][r]);
        s[ti][tj][r] = e;
        sum += e;
      }
    sum += __shfl_xor(sum, 16);
    sum += __shfl_xor(sum, 32);
    rinv[tj] = __builtin_amdgcn_rcpf(sum);
  }

  // pack P (x rinv) as bf16 k-pairs -> swizzled LDS [q=64][k=64]
  unsigned short* Pl = P[wid];
  const unsigned swz = (unsigned)((l15 & 7) << 4);
#pragma unroll
  for (int tj=0; tj<4; ++tj){
    const float rv = rinv[tj];
    const unsigned rowb = (unsigned)((tj*16 + l15)*128);
#pragma unroll
    for (int ti=0; ti<4; ++ti){
      uint2 d;
      d.x = cvt_pk_bf16(s[ti][tj][0]*rv, s[ti][tj][1]*rv);
      d.y = cvt_pk_bf16(s[ti][tj][2]*rv, s[ti][tj][3]*rv);
      unsigned boff = (rowb + (unsigned)(ti*32 + kg*8)) ^ swz;
      *(uint2*)((char*)Pl + boff) = d;
    }
  }

  // O = P @ V
  f32x4 o[4][2] = {};
#pragma unroll
  for (int oti=0; oti<4; ++oti){
    bf16x8 pa[2];
#pragma unroll
    for (int ks=0; ks<2; ++ks){
      unsigned boff = ((unsigned)((oti*16+l15)*128 + ks*64 + kg*16)) ^ swz;
      pa[ks] = *(const bf16x8*)((char*)Pl + boff);
    }
    __builtin_amdgcn_s_setprio(1);
#pragma unroll
    for (int tjv=0; tjv<2; ++tjv){
      o[oti][tjv] = __builtin_amdgcn_mfma_f32_16x16x32_bf16(pa[0], vfk[0][tjv], o[oti][tjv], 0,0,0);
      o[oti][tjv] = __builtin_amdgcn_mfma_f32_16x16x32_bf16(pa[1], vfk[1][tjv], o[oti][tjv], 0,0,0);
    }
    __builtin_amdgcn_s_setprio(0);
  }

  // store rows < 49 (rinv already folded into P)
#pragma unroll
  for (int oti=0; oti<4; ++oti)
#pragma unroll
    for (int r=0; r<4; ++r){
      int row = oti*16 + kg*4 + r;
      if (row < 49){
        unsigned short* op = ao + ((size_t)win*49 + row)*384 + head*32 + l15;
        op[0]  = (unsigned short)cvt_pk_bf16(o[oti][0][r], o[oti][0][r]);
        op[16] = (unsigned short)cvt_pk_bf16(o[oti][1][r], o[oti][1][r]);
      }
    }
}

extern "C" void kernel_launch(void* const* d_in, const int* in_sizes, int n_in,
                              void* d_out, int out_size, void* d_ws, size_t ws_size,
                              hipStream_t stream)
{
  const float* x       = (const float*)d_in[0];   // 32*56*56*384
  const float* w_qkv   = (const float*)d_in[1];   // 1152*384
  const float* b_qkv   = (const float*)d_in[2];   // 1152
  const float* rel_pos = (const float*)d_in[3];   // 12*169
  const float* w_out   = (const float*)d_in[4];   // 384*384
  const float* b_out   = (const float*)d_in[5];   // 384
  float* out = (float*)d_out;                     // 100352*384

  char* ws = (char*)d_ws;
  unsigned short* wqb = (unsigned short*)ws;                  // 884736 B
  unsigned short* wob = (unsigned short*)(ws + 884736);       // 294912 B
  float* btab         = (float*)(ws + 884736 + 294912);       // 196608 B
  unsigned short* qws = (unsigned short*)(ws + 1376256);      // 38535168 elems
  unsigned short* kws = qws + 38535168;
  unsigned short* vws = kws + 38535168;
  unsigned short* xb  = vws + 38535168;   // x_bf during GEMM1, attn-out after
  unsigned short* ao  = xb;               // total ws ~309.7 MB

  prep_kernel<<<dim3(38256), dim3(256), 0, stream>>>(x, w_qkv, w_out, rel_pos,
                                                     xb, wqb, wob, btab);
  gemm256<0,9><<<dim3(3528), dim3(256), 0, stream>>>(xb, wqb, b_qkv, qws, kws, vws, nullptr);
  attn_kernel<<<dim3(6144), dim3(256), 0, stream>>>(qws, kws, vws, btab, ao);
  gemm256<1,3><<<dim3(1176), dim3(256), 0, stream>>>(ao, wob, b_out, nullptr, nullptr, nullptr, out);
}